// Round 9
// baseline (224.439 us; speedup 1.0000x reference)
//
#include <hip/hip_runtime.h>

#define B_ 4
#define C_ 1024
#define T_ 2048
#define NH 16
#define DH 64
#define TC 3072   // 3*C: rows [0,2048)=W_mem (K then V), [2048,3072)=W_q

typedef __attribute__((ext_vector_type(8))) short short8;
typedef __attribute__((ext_vector_type(4))) short short4v;
typedef __attribute__((ext_vector_type(4))) float f32x4;

#define S2Q 0.1803368801111204f   // 0.125 * log2(e), folded into Q at projection

static __device__ __forceinline__ unsigned short f2bf(float f){
  unsigned int u = __builtin_bit_cast(unsigned int, f);
  u += 0x7fffu + ((u >> 16) & 1u);
  return (unsigned short)(u >> 16);
}

// ---------------- cast W_mem||W_q -> bf16 Wc[3072][1024] ----------------
__global__ __launch_bounds__(256) void cast_w_kernel(const float* __restrict__ Wmem,
                                                     const float* __restrict__ Wq,
                                                     unsigned short* __restrict__ Wc){
  size_t base = ((size_t)blockIdx.x*256 + threadIdx.x)*4;
  float4 v;
  if (base < (size_t)2048*1024) v = *(const float4*)(Wmem + base);
  else                          v = *(const float4*)(Wq + (base - (size_t)2048*1024));
  short4v o;
  o.x = (short)f2bf(v.x); o.y = (short)f2bf(v.y);
  o.z = (short)f2bf(v.z); o.w = (short)f2bf(v.w);
  *(short4v*)(Wc + base) = o;
}

// ---------------- mask -> additive float bias (exact ref semantics) ----------------
__global__ __launch_bounds__(256) void mask_bias_kernel(const int* __restrict__ mask,
                                                        float* __restrict__ fbias){
  int i = blockIdx.x*256 + threadIdx.x;
  fbias[i] = mask[i] ? 0.f : -1e30f;
}

// ---------------- transpose-cast x[B][C][T] f32 -> xT[B][T][C] bf16 ----------------
__global__ __launch_bounds__(256) void transpose_x_kernel(const float* __restrict__ x,
                                                          unsigned short* __restrict__ xT){
  __shared__ float tile[32][33];
  int b = blockIdx.z;
  int c0 = blockIdx.y*32, t0 = blockIdx.x*32;
  int tx = threadIdx.x, ty = threadIdx.y;
  const float* xp = x + ((size_t)b*C_ + c0)*T_ + t0;
  #pragma unroll
  for (int i=0;i<4;i++) tile[ty+8*i][tx] = xp[(size_t)(ty+8*i)*T_ + tx];
  __syncthreads();
  unsigned short* op = xT + ((size_t)b*T_ + t0)*C_ + c0;
  #pragma unroll
  for (int i=0;i<4;i++) op[(size_t)(ty+8*i)*C_ + tx] = f2bf(tile[tx][ty+8*i]);
}

// ---------------- projection GEMM (m97 structure; Q pre-scaled by S2Q) ----------------
#define PBM 128
#define PBN 128
#define PBK 64

__global__ __launch_bounds__(256) void proj_gemm_kernel(const unsigned short* __restrict__ Wc,
    const unsigned short* __restrict__ xT,
    unsigned short* __restrict__ Kb, unsigned short* __restrict__ Vt,
    unsigned short* __restrict__ Qb){
  __shared__ unsigned short sA[PBM*PBK];
  __shared__ unsigned short sB[PBN*PBK];
  int b = blockIdx.y;
  int nbn = T_/PBN;
  int o0 = (int)(blockIdx.x / nbn)*PBM;
  int t0 = (int)(blockIdx.x % nbn)*PBN;
  int tid = threadIdx.x;
  int lane = tid & 63, wave = tid >> 6;
  int wr = wave >> 1, wc = wave & 1;
  f32x4 acc[4][4] = {};
  const unsigned short* Abase = Wc + (size_t)o0*C_;
  const unsigned short* Bbase = xT + ((size_t)b*T_ + t0)*C_;
  auto ldsA = (__attribute__((address_space(3))) char*)sA;
  auto ldsB = (__attribute__((address_space(3))) char*)sB;
  for (int k0=0; k0<C_; k0+=PBK){
    #pragma unroll
    for (int i=0;i<4;i++){
      int L  = wave*4096 + i*1024;
      int Ll = L + lane*16;
      int row = Ll >> 7;
      int jb  = Ll & 127;
      const char* srcA = (const char*)(Abase + (size_t)row*C_ + k0) + jb;
      const char* srcB = (const char*)(Bbase + (size_t)row*C_ + k0) + jb;
      __builtin_amdgcn_global_load_lds((const __attribute__((address_space(1))) void*)srcA,
                                       (__attribute__((address_space(3))) void*)(ldsA + L), 16, 0, 0);
      __builtin_amdgcn_global_load_lds((const __attribute__((address_space(1))) void*)srcB,
                                       (__attribute__((address_space(3))) void*)(ldsB + L), 16, 0, 0);
    }
    __syncthreads();
    #pragma unroll
    for (int ks=0; ks<2; ks++){
      short8 af[4], bfr[4];
      #pragma unroll
      for (int m=0;m<4;m++){
        int row = wr*64 + m*16 + (lane & 15);
        af[m] = *(const short8*)((const char*)sA + row*128 + ks*64 + ((lane>>4)*16));
      }
      #pragma unroll
      for (int n=0;n<4;n++){
        int row = wc*64 + n*16 + (lane & 15);
        bfr[n] = *(const short8*)((const char*)sB + row*128 + ks*64 + ((lane>>4)*16));
      }
      #pragma unroll
      for (int m=0;m<4;m++){
        #pragma unroll
        for (int n=0;n<4;n++)
          acc[m][n] = __builtin_amdgcn_mfma_f32_16x16x32_bf16(af[m], bfr[n], acc[m][n], 0, 0, 0);
      }
    }
    __syncthreads();
  }
  int rowbase = o0 + wr*64;
  #pragma unroll
  for (int m=0;m<4;m++){
    int o = rowbase + m*16 + ((lane>>4)*4);
    #pragma unroll
    for (int n=0;n<4;n++){
      int t = t0 + wc*64 + n*16 + (lane & 15);
      f32x4 v = acc[m][n];
      if (o < C_){
        int h = o >> 6, d = o & 63;
        unsigned short* p = Kb + (((size_t)(b*NH + h)*T_ + t)*DH + d);
        short4v s; s.x=(short)f2bf(v.x); s.y=(short)f2bf(v.y);
        s.z=(short)f2bf(v.z); s.w=(short)f2bf(v.w);
        *(short4v*)p = s;
      } else if (o < 2*C_){
        int oo = o - C_;
        int h = oo >> 6, d = oo & 63;
        unsigned short* p = Vt + (((size_t)(b*NH + h)*DH + d)*T_ + t);
        p[0]    = f2bf(v.x);
        p[T_]   = f2bf(v.y);
        p[2*T_] = f2bf(v.z);
        p[3*T_] = f2bf(v.w);
      } else {
        int oo = o - 2*C_;
        int h = oo >> 6, d = oo & 63;
        unsigned short* p = Qb + (((size_t)(b*NH + h)*T_ + t)*DH + d);
        short4v s; s.x=(short)f2bf(v.x*S2Q); s.y=(short)f2bf(v.y*S2Q);
        s.z=(short)f2bf(v.z*S2Q); s.w=(short)f2bf(v.w*S2Q);
        *(short4v*)p = s;
      }
    }
  }
}

// ---------------- flash attention: QBLK=128, shared sP, single bias buffer ----------------
#define KB_ 64

#define GLL(SRC, SHBUF, LOFF) \
  __builtin_amdgcn_global_load_lds((const __attribute__((address_space(1))) void*)(SRC), \
      (__attribute__((address_space(3))) void*)((__attribute__((address_space(3))) char*)(SHBUF) + (LOFF)), 16, 0, 0)

// r6-verbatim per-stream softmax + P-write (sP base is always sPw now)
#define SMAX(SACC, MRUN, LPART, ACCO) do {                                             \
  float m0_ = fmaxf(fmaxf(SACC[0][0],SACC[0][1]),SACC[0][2]);                          \
  float m1_ = fmaxf(fmaxf(SACC[0][3],SACC[1][0]),SACC[1][1]);                          \
  float m2_ = fmaxf(fmaxf(SACC[1][2],SACC[1][3]),SACC[2][0]);                          \
  float m3_ = fmaxf(fmaxf(SACC[2][1],SACC[2][2]),SACC[2][3]);                          \
  float m4_ = fmaxf(fmaxf(SACC[3][0],SACC[3][1]),SACC[3][2]);                          \
  float pmax = fmaxf(fmaxf(fmaxf(m0_,m1_),m2_), fmaxf(fmaxf(m3_,m4_),SACC[3][3]));     \
  if (!__all(pmax - MRUN <= 8.0f)){                                                    \
    float pm = fmaxf(pmax, __shfl_xor(pmax, 16));                                      \
    pm = fmaxf(pm, __shfl_xor(pm, 32));                                                \
    float mnew = fmaxf(MRUN, pm);                                                      \
    float alpha = __builtin_amdgcn_exp2f(MRUN - mnew);                                 \
    MRUN = mnew;                                                                       \
    LPART *= alpha;                                                                    \
    _Pragma("unroll")                                                                  \
    for (int r=0;r<4;r++){                                                             \
      float ar = __shfl(alpha, lg*4 + r);                                              \
      _Pragma("unroll")                                                                \
      for (int nd=0; nd<4; nd++) ACCO[nd][r] *= ar;                                    \
    }                                                                                  \
  }                                                                                    \
  float ps_ = 0.f;                                                                     \
  _Pragma("unroll")                                                                    \
  for (int n=0;n<4;n++){                                                               \
    float p0 = __builtin_amdgcn_exp2f(SACC[n][0] - MRUN);                              \
    float p1 = __builtin_amdgcn_exp2f(SACC[n][1] - MRUN);                              \
    float p2 = __builtin_amdgcn_exp2f(SACC[n][2] - MRUN);                              \
    float p3 = __builtin_amdgcn_exp2f(SACC[n][3] - MRUN);                              \
    ps_ += p0 + p1 + p2 + p3;                                                          \
    unsigned int w0, w1;                                                               \
    asm volatile("v_cvt_pk_bf16_f32 %0, %1, %2" : "=v"(w0) : "v"(p0), "v"(p1));        \
    asm volatile("v_cvt_pk_bf16_f32 %0, %1, %2" : "=v"(w1) : "v"(p2), "v"(p3));        \
    uint2 w; w.x = w0; w.y = w1;                                                       \
    *(uint2*)(sPw + l15*128 + pOff[n]) = w;                                            \
  }                                                                                    \
  LPART += ps_;                                                                        \
} while(0)

// PV for one stream: pf from shared sP, vf from sVb (re-read per stream)
#define PV(ACCO) do {                                                                  \
  asm volatile("s_waitcnt lgkmcnt(0)" ::: "memory");                                   \
  __builtin_amdgcn_sched_barrier(0);                                                   \
  __builtin_amdgcn_s_setprio(1);                                                       \
  _Pragma("unroll")                                                                    \
  for (int ks=0; ks<2; ks++){                                                          \
    short8 pf = *(const short8*)(sPw + l15*128 + (cA ^ (ks<<6)));                      \
    _Pragma("unroll")                                                                  \
    for (int nd=0; nd<4; nd++){                                                        \
      short8 vf = *(const short8*)(sVb + nd*2048 + (cA ^ (ks<<6)));                    \
      ACCO[nd] = __builtin_amdgcn_mfma_f32_16x16x32_bf16(pf, vf, ACCO[nd], 0,0,0);     \
    }                                                                                  \
  }                                                                                    \
  __builtin_amdgcn_s_setprio(0);                                                       \
} while(0)

#define TILE(CBUF, DOSTAGE, DOPRE) do {                                                \
  if (DOSTAGE) {                                                                       \
    GLL(srcK0, &sK[(CBUF)^1][0], L0);                                                  \
    GLL(srcK1, &sK[(CBUF)^1][0], L0 + 1024);                                           \
    GLL(srcV0, &sV[(CBUF)^1][0], L0);                                                  \
    GLL(srcV1, &sV[(CBUF)^1][0], L0 + 1024);                                           \
    srcK0 += 8192; srcK1 += 8192; srcV0 += 128; srcV1 += 128;                          \
  }                                                                                    \
  const char* sKb = (const char*)&sK[CBUF][0] + l15*128;                               \
  const char* sVb = (const char*)&sV[CBUF][0] + l15*128;                               \
  f32x4 sacc0[4], sacc1[4];                                                            \
  __builtin_amdgcn_s_setprio(1);                                                       \
  _Pragma("unroll")                                                                    \
  for (int n=0;n<4;n++){                                                               \
    short8 kf0 = *(const short8*)(sKb + n*2048 + cA);                                  \
    short8 kf1 = *(const short8*)(sKb + n*2048 + (cA ^ 64));                           \
    sacc0[n] = __builtin_amdgcn_mfma_f32_16x16x32_bf16(kf0, qf00, biasC[n], 0,0,0);    \
    sacc0[n] = __builtin_amdgcn_mfma_f32_16x16x32_bf16(kf1, qf01, sacc0[n], 0,0,0);    \
    sacc1[n] = __builtin_amdgcn_mfma_f32_16x16x32_bf16(kf0, qf10, biasC[n], 0,0,0);    \
    sacc1[n] = __builtin_amdgcn_mfma_f32_16x16x32_bf16(kf1, qf11, sacc1[n], 0,0,0);    \
  }                                                                                    \
  __builtin_amdgcn_s_setprio(0);                                                       \
  if (DOPRE) {                                                                         \
    bptr += 64;                                                                        \
    _Pragma("unroll")                                                                  \
    for (int n=0;n<4;n++) biasC[n] = *(const f32x4*)(bptr + n*16);                     \
  }                                                                                    \
  SMAX(sacc0, mrun0, lpart0, acco0);                                                   \
  PV(acco0);                                                                           \
  SMAX(sacc1, mrun1, lpart1, acco1);                                                   \
  PV(acco1);                                                                           \
  __syncthreads();                                                                     \
} while(0)

#define EPI(ACCO, LPART, TOFF) do {                                                    \
  float lt = LPART + __shfl_xor(LPART, 16);                                            \
  lt += __shfl_xor(lt, 32);                                                            \
  float rl[4];                                                                         \
  _Pragma("unroll")                                                                    \
  for (int r=0;r<4;r++) rl[r] = 1.0f / __shfl(lt, lg*4 + r);                           \
  _Pragma("unroll")                                                                    \
  for (int nd=0; nd<4; nd++){                                                          \
    int d = nd*16 + l15;                                                               \
    int c = h*64 + d;                                                                  \
    float4 v;                                                                          \
    v.x = ACCO[nd][0] * rl[0];                                                         \
    v.y = ACCO[nd][1] * rl[1];                                                         \
    v.z = ACCO[nd][2] * rl[2];                                                         \
    v.w = ACCO[nd][3] * rl[3];                                                         \
    size_t off = ((size_t)b*C_ + c)*T_ + (size_t)qblk*128 + wave*32 + (TOFF) + lg*4;   \
    *(float4*)(out + off) = v;                                                         \
  }                                                                                    \
} while(0)

__global__ __launch_bounds__(256) void attn_kernel(const unsigned short* __restrict__ Qb,
    const unsigned short* __restrict__ Kb, const unsigned short* __restrict__ Vt,
    const float* __restrict__ fbias, float* __restrict__ out){
  __shared__ unsigned short sK[2][KB_*DH];   // [key][d] swizzled, dbuf (8KB each)
  __shared__ unsigned short sV[2][KB_*DH];   // [d][key] swizzled, dbuf
  __shared__ unsigned short sP[4][16*KB_];   // per-wave [q(l15)][key], shared by both streams
  const int qblk = blockIdx.x, bh = blockIdx.y, b = bh >> 4;
  const int tid = threadIdx.x, lane = tid & 63, wave = tid >> 6;
  const int l15 = lane & 15, lg = lane >> 4;
  const int rsw = l15 & 7;
  const int cA = (lg ^ rsw) << 4;
  const unsigned short* Kbase = Kb + (size_t)bh*T_*DH;
  const unsigned short* Vbase = Vt + (size_t)bh*DH*T_;
  const float* bptr = fbias + (size_t)b*T_ + lg*4;
  // Q: two 16-row streams per wave
  const int qrow0 = qblk*128 + wave*32 + l15;
  const unsigned short* Qp0 = Qb + ((size_t)bh*T_ + qrow0)*DH + lg*8;
  const unsigned short* Qp1 = Qp0 + 16*DH;
  short8 qf00 = *(const short8*)(Qp0);
  short8 qf01 = *(const short8*)(Qp0 + 32);
  short8 qf10 = *(const short8*)(Qp1);
  short8 qf11 = *(const short8*)(Qp1 + 32);
  f32x4 acco0[4] = {};                 // stream 0: out[q=lg*4+r][d=nd*16+l15]
  f32x4 acco1[4] = {};                 // stream 1
  float mrun0 = -1e30f, lpart0 = 0.f;
  float mrun1 = -1e30f, lpart1 = 0.f;
  // staging source addresses (inverse swizzle), proven four-pointer form
  const int L0  = wave*2048;
  const int Ll0 = L0 + lane*16, Ll1 = Ll0 + 1024;
  const int row0 = Ll0 >> 7, row1 = Ll1 >> 7;
  const int cg0 = ((Ll0 >> 4) & 7) ^ (row0 & 7);
  const int cg1 = ((Ll1 >> 4) & 7) ^ (row1 & 7);
  const char* srcK0 = (const char*)Kbase + row0*128 + cg0*16;
  const char* srcK1 = (const char*)Kbase + row1*128 + cg1*16;
  const char* srcV0 = (const char*)Vbase + (size_t)row0*(T_*2) + cg0*16;
  const char* srcV1 = (const char*)Vbase + (size_t)row1*(T_*2) + cg1*16;
  char* sPw = (char*)&sP[wave][0];
  int pOff[4];
  #pragma unroll
  for (int n=0;n<4;n++) pOff[n] = (((n*2 + (lg>>1)) ^ rsw) << 4) | ((lg & 1) << 3);

  // prologue: stage tile 0, load bias(0)
  GLL(srcK0, &sK[0][0], L0);
  GLL(srcK1, &sK[0][0], L0 + 1024);
  GLL(srcV0, &sV[0][0], L0);
  GLL(srcV1, &sV[0][0], L0 + 1024);
  srcK0 += 8192; srcK1 += 8192; srcV0 += 128; srcV1 += 128;
  f32x4 biasC[4];
  #pragma unroll
  for (int n=0;n<4;n++) biasC[n] = *(const f32x4*)(bptr + n*16);
  __syncthreads();

  for (int kt2 = 0; kt2 < T_/KB_/2 - 1; kt2++){
    TILE(0, true, true);
    TILE(1, true, true);
  }
  TILE(0, true, true);    // kt=30, stages tile 31, loads bias(31)
  TILE(1, false, false);  // kt=31

  int h = bh & 15;
  EPI(acco0, lpart0, 0);
  EPI(acco1, lpart1, 16);
}

extern "C" void kernel_launch(void* const* d_in, const int* in_sizes, int n_in,
                              void* d_out, int out_size, void* d_ws, size_t ws_size,
                              hipStream_t stream) {
  const float* x    = (const float*)d_in[0];
  const int*   mask = (const int*)d_in[1];
  const float* Wmem = (const float*)d_in[2];
  const float* Wq   = (const float*)d_in[3];
  float* out = (float*)d_out;

  unsigned short* ws = (unsigned short*)d_ws;
  unsigned short* xT = ws;                                   // B*T*C
  unsigned short* Wc = xT + (size_t)B_*T_*C_;                // TC*C
  unsigned short* Qb = Wc + (size_t)TC*C_;                   // B*NH*T*DH
  unsigned short* Kb = Qb + (size_t)B_*NH*T_*DH;
  unsigned short* Vt = Kb + (size_t)B_*NH*T_*DH;
  float* fbias = (float*)(Vt + (size_t)B_*NH*T_*DH);         // B*T floats

  cast_w_kernel<<<dim3(TC*C_/1024), dim3(256), 0, stream>>>(Wmem, Wq, Wc);
  mask_bias_kernel<<<dim3(B_*T_/256), dim3(256), 0, stream>>>(mask, fbias);
  transpose_x_kernel<<<dim3(T_/32, C_/32, B_), dim3(32,8), 0, stream>>>(x, xT);
  proj_gemm_kernel<<<dim3((TC/PBM)*(T_/PBN), B_), dim3(256), 0, stream>>>(Wc, xT, Kb, Vt, Qb);
  attn_kernel<<<dim3(T_/128, B_*NH), dim3(256), 0, stream>>>(Qb, Kb, Vt, fbias, out);
}

// Round 10
// 211.113 us; speedup vs baseline: 1.0631x; 1.0631x over previous
//
#include <hip/hip_runtime.h>

#define B_ 4
#define C_ 1024
#define T_ 2048
#define NH 16
#define DH 64
#define TC 3072   // 3*C: rows [0,2048)=W_mem (K then V), [2048,3072)=W_q

typedef __attribute__((ext_vector_type(8))) short short8;
typedef __attribute__((ext_vector_type(4))) short short4v;
typedef __attribute__((ext_vector_type(4))) float f32x4;

#define S2Q 0.1803368801111204f   // 0.125 * log2(e), folded into Q at projection

static __device__ __forceinline__ unsigned short f2bf(float f){
  unsigned int u = __builtin_bit_cast(unsigned int, f);
  u += 0x7fffu + ((u >> 16) & 1u);
  return (unsigned short)(u >> 16);
}

// ---------------- cast W_mem||W_q -> bf16 Wc[3072][1024] ----------------
__global__ __launch_bounds__(256) void cast_w_kernel(const float* __restrict__ Wmem,
                                                     const float* __restrict__ Wq,
                                                     unsigned short* __restrict__ Wc){
  size_t base = ((size_t)blockIdx.x*256 + threadIdx.x)*4;
  float4 v;
  if (base < (size_t)2048*1024) v = *(const float4*)(Wmem + base);
  else                          v = *(const float4*)(Wq + (base - (size_t)2048*1024));
  short4v o;
  o.x = (short)f2bf(v.x); o.y = (short)f2bf(v.y);
  o.z = (short)f2bf(v.z); o.w = (short)f2bf(v.w);
  *(short4v*)(Wc + base) = o;
}

// ---------------- mask -> additive float bias (exact ref semantics) ----------------
__global__ __launch_bounds__(256) void mask_bias_kernel(const int* __restrict__ mask,
                                                        float* __restrict__ fbias){
  int i = blockIdx.x*256 + threadIdx.x;
  fbias[i] = mask[i] ? 0.f : -1e30f;
}

// ---------------- transpose-cast x[B][C][T] f32 -> xT[B][T][C] bf16 ----------------
__global__ __launch_bounds__(256) void transpose_x_kernel(const float* __restrict__ x,
                                                          unsigned short* __restrict__ xT){
  __shared__ float tile[32][33];
  int b = blockIdx.z;
  int c0 = blockIdx.y*32, t0 = blockIdx.x*32;
  int tx = threadIdx.x, ty = threadIdx.y;
  const float* xp = x + ((size_t)b*C_ + c0)*T_ + t0;
  #pragma unroll
  for (int i=0;i<4;i++) tile[ty+8*i][tx] = xp[(size_t)(ty+8*i)*T_ + tx];
  __syncthreads();
  unsigned short* op = xT + ((size_t)b*T_ + t0)*C_ + c0;
  #pragma unroll
  for (int i=0;i<4;i++) op[(size_t)(ty+8*i)*C_ + tx] = f2bf(tile[tx][ty+8*i]);
}

// ---------------- projection GEMM (m97 structure; Q pre-scaled by S2Q) ----------------
#define PBM 128
#define PBN 128
#define PBK 64

__global__ __launch_bounds__(256) void proj_gemm_kernel(const unsigned short* __restrict__ Wc,
    const unsigned short* __restrict__ xT,
    unsigned short* __restrict__ Kb, unsigned short* __restrict__ Vt,
    unsigned short* __restrict__ Qb){
  __shared__ unsigned short sA[PBM*PBK];
  __shared__ unsigned short sB[PBN*PBK];
  int b = blockIdx.y;
  int nbn = T_/PBN;
  int o0 = (int)(blockIdx.x / nbn)*PBM;
  int t0 = (int)(blockIdx.x % nbn)*PBN;
  int tid = threadIdx.x;
  int lane = tid & 63, wave = tid >> 6;
  int wr = wave >> 1, wc = wave & 1;
  f32x4 acc[4][4] = {};
  const unsigned short* Abase = Wc + (size_t)o0*C_;
  const unsigned short* Bbase = xT + ((size_t)b*T_ + t0)*C_;
  auto ldsA = (__attribute__((address_space(3))) char*)sA;
  auto ldsB = (__attribute__((address_space(3))) char*)sB;
  for (int k0=0; k0<C_; k0+=PBK){
    #pragma unroll
    for (int i=0;i<4;i++){
      int L  = wave*4096 + i*1024;
      int Ll = L + lane*16;
      int row = Ll >> 7;
      int jb  = Ll & 127;
      const char* srcA = (const char*)(Abase + (size_t)row*C_ + k0) + jb;
      const char* srcB = (const char*)(Bbase + (size_t)row*C_ + k0) + jb;
      __builtin_amdgcn_global_load_lds((const __attribute__((address_space(1))) void*)srcA,
                                       (__attribute__((address_space(3))) void*)(ldsA + L), 16, 0, 0);
      __builtin_amdgcn_global_load_lds((const __attribute__((address_space(1))) void*)srcB,
                                       (__attribute__((address_space(3))) void*)(ldsB + L), 16, 0, 0);
    }
    __syncthreads();
    #pragma unroll
    for (int ks=0; ks<2; ks++){
      short8 af[4], bfr[4];
      #pragma unroll
      for (int m=0;m<4;m++){
        int row = wr*64 + m*16 + (lane & 15);
        af[m] = *(const short8*)((const char*)sA + row*128 + ks*64 + ((lane>>4)*16));
      }
      #pragma unroll
      for (int n=0;n<4;n++){
        int row = wc*64 + n*16 + (lane & 15);
        bfr[n] = *(const short8*)((const char*)sB + row*128 + ks*64 + ((lane>>4)*16));
      }
      #pragma unroll
      for (int m=0;m<4;m++){
        #pragma unroll
        for (int n=0;n<4;n++)
          acc[m][n] = __builtin_amdgcn_mfma_f32_16x16x32_bf16(af[m], bfr[n], acc[m][n], 0, 0, 0);
      }
    }
    __syncthreads();
  }
  int rowbase = o0 + wr*64;
  #pragma unroll
  for (int m=0;m<4;m++){
    int o = rowbase + m*16 + ((lane>>4)*4);
    #pragma unroll
    for (int n=0;n<4;n++){
      int t = t0 + wc*64 + n*16 + (lane & 15);
      f32x4 v = acc[m][n];
      if (o < C_){
        int h = o >> 6, d = o & 63;
        unsigned short* p = Kb + (((size_t)(b*NH + h)*T_ + t)*DH + d);
        short4v s; s.x=(short)f2bf(v.x); s.y=(short)f2bf(v.y);
        s.z=(short)f2bf(v.z); s.w=(short)f2bf(v.w);
        *(short4v*)p = s;
      } else if (o < 2*C_){
        int oo = o - C_;
        int h = oo >> 6, d = oo & 63;
        unsigned short* p = Vt + (((size_t)(b*NH + h)*DH + d)*T_ + t);
        p[0]    = f2bf(v.x);
        p[T_]   = f2bf(v.y);
        p[2*T_] = f2bf(v.z);
        p[3*T_] = f2bf(v.w);
      } else {
        int oo = o - 2*C_;
        int h = oo >> 6, d = oo & 63;
        unsigned short* p = Qb + (((size_t)(b*NH + h)*T_ + t)*DH + d);
        short4v s; s.x=(short)f2bf(v.x*S2Q); s.y=(short)f2bf(v.y*S2Q);
        s.z=(short)f2bf(v.z*S2Q); s.w=(short)f2bf(v.w*S2Q);
        *(short4v*)p = s;
      }
    }
  }
}

// ---------------- flash attention: QBLK=128 (r8 structure) + XCD-local bh grouping ----------------
#define KB_ 64

#define GLL(SRC, SHBUF, LOFF) \
  __builtin_amdgcn_global_load_lds((const __attribute__((address_space(1))) void*)(SRC), \
      (__attribute__((address_space(3))) void*)((__attribute__((address_space(3))) char*)(SHBUF) + (LOFF)), 16, 0, 0)

// r6-verbatim per-stream softmax + P-write
#define SMAX(SACC, MRUN, LPART, ACCO, PBASE) do {                                      \
  float m0_ = fmaxf(fmaxf(SACC[0][0],SACC[0][1]),SACC[0][2]);                          \
  float m1_ = fmaxf(fmaxf(SACC[0][3],SACC[1][0]),SACC[1][1]);                          \
  float m2_ = fmaxf(fmaxf(SACC[1][2],SACC[1][3]),SACC[2][0]);                          \
  float m3_ = fmaxf(fmaxf(SACC[2][1],SACC[2][2]),SACC[2][3]);                          \
  float m4_ = fmaxf(fmaxf(SACC[3][0],SACC[3][1]),SACC[3][2]);                          \
  float pmax = fmaxf(fmaxf(fmaxf(m0_,m1_),m2_), fmaxf(fmaxf(m3_,m4_),SACC[3][3]));     \
  if (!__all(pmax - MRUN <= 8.0f)){                                                    \
    float pm = fmaxf(pmax, __shfl_xor(pmax, 16));                                      \
    pm = fmaxf(pm, __shfl_xor(pm, 32));                                                \
    float mnew = fmaxf(MRUN, pm);                                                      \
    float alpha = __builtin_amdgcn_exp2f(MRUN - mnew);                                 \
    MRUN = mnew;                                                                       \
    LPART *= alpha;                                                                    \
    _Pragma("unroll")                                                                  \
    for (int r=0;r<4;r++){                                                             \
      float ar = __shfl(alpha, lg*4 + r);                                              \
      _Pragma("unroll")                                                                \
      for (int nd=0; nd<4; nd++) ACCO[nd][r] *= ar;                                    \
    }                                                                                  \
  }                                                                                    \
  float ps_ = 0.f;                                                                     \
  _Pragma("unroll")                                                                    \
  for (int n=0;n<4;n++){                                                               \
    float p0 = __builtin_amdgcn_exp2f(SACC[n][0] - MRUN);                              \
    float p1 = __builtin_amdgcn_exp2f(SACC[n][1] - MRUN);                              \
    float p2 = __builtin_amdgcn_exp2f(SACC[n][2] - MRUN);                              \
    float p3 = __builtin_amdgcn_exp2f(SACC[n][3] - MRUN);                              \
    ps_ += p0 + p1 + p2 + p3;                                                          \
    unsigned int w0, w1;                                                               \
    asm volatile("v_cvt_pk_bf16_f32 %0, %1, %2" : "=v"(w0) : "v"(p0), "v"(p1));        \
    asm volatile("v_cvt_pk_bf16_f32 %0, %1, %2" : "=v"(w1) : "v"(p2), "v"(p3));        \
    uint2 w; w.x = w0; w.y = w1;                                                       \
    *(uint2*)(sPw + (PBASE) + l15*128 + pOff[n]) = w;                                  \
  }                                                                                    \
  LPART += ps_;                                                                        \
} while(0)

#define TILE(CBUF, BUSE, BPRE, POFF, DOSTAGE, DOPRE) do {                              \
  if (DOSTAGE) {                                                                       \
    GLL(srcK0, &sK[(CBUF)^1][0], L0);                                                  \
    GLL(srcK1, &sK[(CBUF)^1][0], L0 + 1024);                                           \
    GLL(srcV0, &sV[(CBUF)^1][0], L0);                                                  \
    GLL(srcV1, &sV[(CBUF)^1][0], L0 + 1024);                                           \
    srcK0 += 8192; srcK1 += 8192; srcV0 += 128; srcV1 += 128;                          \
  }                                                                                    \
  if (DOPRE) {                                                                         \
    _Pragma("unroll")                                                                  \
    for (int n=0;n<4;n++) BPRE[n] = *(const f32x4*)(bptr + (POFF) + n*16);             \
  }                                                                                    \
  const char* sKb = (const char*)&sK[CBUF][0] + l15*128;                               \
  const char* sVb = (const char*)&sV[CBUF][0] + l15*128;                               \
  f32x4 sacc0[4], sacc1[4];                                                            \
  __builtin_amdgcn_s_setprio(1);                                                       \
  _Pragma("unroll")                                                                    \
  for (int n=0;n<4;n++){                                                               \
    short8 kf0 = *(const short8*)(sKb + n*2048 + cA);                                  \
    short8 kf1 = *(const short8*)(sKb + n*2048 + (cA ^ 64));                           \
    sacc0[n] = __builtin_amdgcn_mfma_f32_16x16x32_bf16(kf0, qf00, BUSE[n], 0,0,0);     \
    sacc0[n] = __builtin_amdgcn_mfma_f32_16x16x32_bf16(kf1, qf01, sacc0[n], 0,0,0);    \
    sacc1[n] = __builtin_amdgcn_mfma_f32_16x16x32_bf16(kf0, qf10, BUSE[n], 0,0,0);     \
    sacc1[n] = __builtin_amdgcn_mfma_f32_16x16x32_bf16(kf1, qf11, sacc1[n], 0,0,0);    \
  }                                                                                    \
  __builtin_amdgcn_s_setprio(0);                                                       \
  SMAX(sacc0, mrun0, lpart0, acco0, 0);                                                \
  SMAX(sacc1, mrun1, lpart1, acco1, 2048);                                             \
  asm volatile("s_waitcnt lgkmcnt(0)" ::: "memory");                                   \
  __builtin_amdgcn_sched_barrier(0);                                                   \
  __builtin_amdgcn_s_setprio(1);                                                       \
  _Pragma("unroll")                                                                    \
  for (int ks=0; ks<2; ks++){                                                          \
    short8 pf0 = *(const short8*)(sPw + l15*128 + (cA ^ (ks<<6)));                     \
    short8 pf1 = *(const short8*)(sPw + 2048 + l15*128 + (cA ^ (ks<<6)));              \
    _Pragma("unroll")                                                                  \
    for (int nd=0; nd<4; nd++){                                                        \
      short8 vf = *(const short8*)(sVb + nd*2048 + (cA ^ (ks<<6)));                    \
      acco0[nd] = __builtin_amdgcn_mfma_f32_16x16x32_bf16(pf0, vf, acco0[nd], 0,0,0);  \
      acco1[nd] = __builtin_amdgcn_mfma_f32_16x16x32_bf16(pf1, vf, acco1[nd], 0,0,0);  \
    }                                                                                  \
  }                                                                                    \
  __builtin_amdgcn_s_setprio(0);                                                       \
  __syncthreads();                                                                     \
} while(0)

#define EPI(ACCO, LPART, TOFF) do {                                                    \
  float lt = LPART + __shfl_xor(LPART, 16);                                            \
  lt += __shfl_xor(lt, 32);                                                            \
  float rl[4];                                                                         \
  _Pragma("unroll")                                                                    \
  for (int r=0;r<4;r++) rl[r] = 1.0f / __shfl(lt, lg*4 + r);                           \
  _Pragma("unroll")                                                                    \
  for (int nd=0; nd<4; nd++){                                                          \
    int d = nd*16 + l15;                                                               \
    int c = h*64 + d;                                                                  \
    float4 v;                                                                          \
    v.x = ACCO[nd][0] * rl[0];                                                         \
    v.y = ACCO[nd][1] * rl[1];                                                         \
    v.z = ACCO[nd][2] * rl[2];                                                         \
    v.w = ACCO[nd][3] * rl[3];                                                         \
    size_t off = ((size_t)b*C_ + c)*T_ + (size_t)qblk*128 + wave*32 + (TOFF) + lg*4;   \
    *(float4*)(out + off) = v;                                                         \
  }                                                                                    \
} while(0)

__global__ __launch_bounds__(256) void attn_kernel(const unsigned short* __restrict__ Qb,
    const unsigned short* __restrict__ Kb, const unsigned short* __restrict__ Vt,
    const float* __restrict__ fbias, float* __restrict__ out){
  __shared__ unsigned short sK[2][KB_*DH];      // [key][d] swizzled, dbuf (8KB each)
  __shared__ unsigned short sV[2][KB_*DH];      // [d][key] swizzled, dbuf
  __shared__ unsigned short sP[4][2][16*KB_];   // per-wave, per-stream [q(l15)][key] swizzled
  // XCD-local remap: all 16 qblk-blocks of one bh share L%8 -> same XCD L2 holds its K/V panel.
  // Bijective: L = ((qblk*8 + (bh>>3))<<3) | (bh&7).
  const int Lid = blockIdx.x;
  const int xcd = Lid & 7, jj = Lid >> 3;
  const int bh = ((jj & 7) << 3) | xcd;
  const int qblk = jj >> 3;
  const int b = bh >> 4;
  const int tid = threadIdx.x, lane = tid & 63, wave = tid >> 6;
  const int l15 = lane & 15, lg = lane >> 4;
  const int rsw = l15 & 7;
  const int cA = (lg ^ rsw) << 4;
  const unsigned short* Kbase = Kb + (size_t)bh*T_*DH;
  const unsigned short* Vbase = Vt + (size_t)bh*DH*T_;
  const float* bptr = fbias + (size_t)b*T_ + lg*4;
  // Q: two 16-row streams per wave
  const int qrow0 = qblk*128 + wave*32 + l15;
  const unsigned short* Qp0 = Qb + ((size_t)bh*T_ + qrow0)*DH + lg*8;
  const unsigned short* Qp1 = Qp0 + 16*DH;
  short8 qf00 = *(const short8*)(Qp0);
  short8 qf01 = *(const short8*)(Qp0 + 32);
  short8 qf10 = *(const short8*)(Qp1);
  short8 qf11 = *(const short8*)(Qp1 + 32);
  f32x4 acco0[4] = {};                 // stream 0: out[q=lg*4+r][d=nd*16+l15]
  f32x4 acco1[4] = {};                 // stream 1
  float mrun0 = -1e30f, lpart0 = 0.f;
  float mrun1 = -1e30f, lpart1 = 0.f;
  // staging source addresses (inverse swizzle), proven four-pointer form
  const int L0  = wave*2048;
  const int Ll0 = L0 + lane*16, Ll1 = Ll0 + 1024;
  const int row0 = Ll0 >> 7, row1 = Ll1 >> 7;
  const int cg0 = ((Ll0 >> 4) & 7) ^ (row0 & 7);
  const int cg1 = ((Ll1 >> 4) & 7) ^ (row1 & 7);
  const char* srcK0 = (const char*)Kbase + row0*128 + cg0*16;
  const char* srcK1 = (const char*)Kbase + row1*128 + cg1*16;
  const char* srcV0 = (const char*)Vbase + (size_t)row0*(T_*2) + cg0*16;
  const char* srcV1 = (const char*)Vbase + (size_t)row1*(T_*2) + cg1*16;
  char* sPw = (char*)&sP[wave][0][0];
  int pOff[4];
  #pragma unroll
  for (int n=0;n<4;n++) pOff[n] = (((n*2 + (lg>>1)) ^ rsw) << 4) | ((lg & 1) << 3);

  // prologue: stage tile 0, preload bias(0)
  GLL(srcK0, &sK[0][0], L0);
  GLL(srcK1, &sK[0][0], L0 + 1024);
  GLL(srcV0, &sV[0][0], L0);
  GLL(srcV1, &sV[0][0], L0 + 1024);
  srcK0 += 8192; srcK1 += 8192; srcV0 += 128; srcV1 += 128;
  f32x4 biasA[4], biasB[4];
  #pragma unroll
  for (int n=0;n<4;n++) biasA[n] = *(const f32x4*)(bptr + n*16);
  __syncthreads();

  for (int kt2 = 0; kt2 < T_/KB_/2 - 1; kt2++){
    TILE(0, biasA, biasB,  64, true, true);
    TILE(1, biasB, biasA, 128, true, true);
    bptr += 128;
  }
  TILE(0, biasA, biasB, 64, true, true);    // kt=30, stages tile 31
  TILE(1, biasB, biasA,  0, false, false);  // kt=31

  int h = bh & 15;
  EPI(acco0, lpart0, 0);
  EPI(acco1, lpart1, 16);
}

extern "C" void kernel_launch(void* const* d_in, const int* in_sizes, int n_in,
                              void* d_out, int out_size, void* d_ws, size_t ws_size,
                              hipStream_t stream) {
  const float* x    = (const float*)d_in[0];
  const int*   mask = (const int*)d_in[1];
  const float* Wmem = (const float*)d_in[2];
  const float* Wq   = (const float*)d_in[3];
  float* out = (float*)d_out;

  unsigned short* ws = (unsigned short*)d_ws;
  unsigned short* xT = ws;                                   // B*T*C
  unsigned short* Wc = xT + (size_t)B_*T_*C_;                // TC*C
  unsigned short* Qb = Wc + (size_t)TC*C_;                   // B*NH*T*DH
  unsigned short* Kb = Qb + (size_t)B_*NH*T_*DH;
  unsigned short* Vt = Kb + (size_t)B_*NH*T_*DH;
  float* fbias = (float*)(Vt + (size_t)B_*NH*T_*DH);         // B*T floats

  cast_w_kernel<<<dim3(TC*C_/1024), dim3(256), 0, stream>>>(Wmem, Wq, Wc);
  mask_bias_kernel<<<dim3(B_*T_/256), dim3(256), 0, stream>>>(mask, fbias);
  transpose_x_kernel<<<dim3(T_/32, C_/32, B_), dim3(32,8), 0, stream>>>(x, xT);
  proj_gemm_kernel<<<dim3((TC/PBM)*(T_/PBN), B_), dim3(256), 0, stream>>>(Wc, xT, Kb, Vt, Qb);
  attn_kernel<<<dim3((T_/128)*(B_*NH)), dim3(256), 0, stream>>>(Qb, Kb, Vt, fbias, out);
}

// Round 11
// 206.812 us; speedup vs baseline: 1.0852x; 1.0208x over previous
//
#include <hip/hip_runtime.h>

#define B_ 4
#define C_ 1024
#define T_ 2048
#define NH 16
#define DH 64
#define TC 3072   // 3*C: rows [0,2048)=W_mem (K then V), [2048,3072)=W_q

typedef __attribute__((ext_vector_type(8))) short short8;
typedef __attribute__((ext_vector_type(4))) short short4v;
typedef __attribute__((ext_vector_type(4))) float f32x4;

#define S2Q 0.1803368801111204f   // 0.125 * log2(e), folded into Q at projection

static __device__ __forceinline__ unsigned short f2bf(float f){
  unsigned int u = __builtin_bit_cast(unsigned int, f);
  u += 0x7fffu + ((u >> 16) & 1u);
  return (unsigned short)(u >> 16);
}

// ---------------- cast W_mem||W_q -> bf16 Wc[3072][1024] ----------------
__global__ __launch_bounds__(256) void cast_w_kernel(const float* __restrict__ Wmem,
                                                     const float* __restrict__ Wq,
                                                     unsigned short* __restrict__ Wc){
  size_t base = ((size_t)blockIdx.x*256 + threadIdx.x)*4;
  float4 v;
  if (base < (size_t)2048*1024) v = *(const float4*)(Wmem + base);
  else                          v = *(const float4*)(Wq + (base - (size_t)2048*1024));
  short4v o;
  o.x = (short)f2bf(v.x); o.y = (short)f2bf(v.y);
  o.z = (short)f2bf(v.z); o.w = (short)f2bf(v.w);
  *(short4v*)(Wc + base) = o;
}

// ---------------- mask -> additive float bias (exact ref semantics) ----------------
__global__ __launch_bounds__(256) void mask_bias_kernel(const int* __restrict__ mask,
                                                        float* __restrict__ fbias){
  int i = blockIdx.x*256 + threadIdx.x;
  fbias[i] = mask[i] ? 0.f : -1e30f;
}

// ---------------- transpose-cast x[B][C][T] f32 -> xT[B][T][C] bf16 ----------------
// reads 4B/lane coalesced; writes packed bf16x2 (4B/lane) coalesced.
__global__ __launch_bounds__(256) void transpose_x_kernel(const float* __restrict__ x,
                                                          unsigned short* __restrict__ xT){
  __shared__ float tile[32][33];
  int b = blockIdx.z;
  int c0 = blockIdx.y*32, t0 = blockIdx.x*32;
  int tx = threadIdx.x, ty = threadIdx.y;
  const float* xp = x + ((size_t)b*C_ + c0)*T_ + t0;
  #pragma unroll
  for (int i=0;i<4;i++) tile[ty+8*i][tx] = xp[(size_t)(ty+8*i)*T_ + tx];
  __syncthreads();
  unsigned short* op = xT + ((size_t)b*T_ + t0)*C_ + c0;
  int cp = tx & 15, tw = tx >> 4;
  #pragma unroll
  for (int i=0;i<2;i++){
    int trow = ty + 8*tw + 16*i;
    unsigned int pk = (unsigned int)f2bf(tile[2*cp][trow])
                    | ((unsigned int)f2bf(tile[2*cp+1][trow]) << 16);
    *(unsigned int*)(op + (size_t)trow*C_ + 2*cp) = pk;
  }
}

// ---------------- projection GEMM (m97 structure; Q pre-scaled by S2Q) ----------------
#define PBM 128
#define PBN 128
#define PBK 64

__global__ __launch_bounds__(256) void proj_gemm_kernel(const unsigned short* __restrict__ Wc,
    const unsigned short* __restrict__ xT,
    unsigned short* __restrict__ Kb, unsigned short* __restrict__ Vt,
    unsigned short* __restrict__ Qb){
  __shared__ unsigned short sA[PBM*PBK];
  __shared__ unsigned short sB[PBN*PBK];
  int b = blockIdx.y;
  int nbn = T_/PBN;
  int o0 = (int)(blockIdx.x / nbn)*PBM;
  int t0 = (int)(blockIdx.x % nbn)*PBN;
  int tid = threadIdx.x;
  int lane = tid & 63, wave = tid >> 6;
  int wr = wave >> 1, wc = wave & 1;
  f32x4 acc[4][4] = {};
  const unsigned short* Abase = Wc + (size_t)o0*C_;
  const unsigned short* Bbase = xT + ((size_t)b*T_ + t0)*C_;
  auto ldsA = (__attribute__((address_space(3))) char*)sA;
  auto ldsB = (__attribute__((address_space(3))) char*)sB;
  for (int k0=0; k0<C_; k0+=PBK){
    #pragma unroll
    for (int i=0;i<4;i++){
      int L  = wave*4096 + i*1024;
      int Ll = L + lane*16;
      int row = Ll >> 7;
      int jb  = Ll & 127;
      const char* srcA = (const char*)(Abase + (size_t)row*C_ + k0) + jb;
      const char* srcB = (const char*)(Bbase + (size_t)row*C_ + k0) + jb;
      __builtin_amdgcn_global_load_lds((const __attribute__((address_space(1))) void*)srcA,
                                       (__attribute__((address_space(3))) void*)(ldsA + L), 16, 0, 0);
      __builtin_amdgcn_global_load_lds((const __attribute__((address_space(1))) void*)srcB,
                                       (__attribute__((address_space(3))) void*)(ldsB + L), 16, 0, 0);
    }
    __syncthreads();
    #pragma unroll
    for (int ks=0; ks<2; ks++){
      short8 af[4], bfr[4];
      #pragma unroll
      for (int m=0;m<4;m++){
        int row = wr*64 + m*16 + (lane & 15);
        af[m] = *(const short8*)((const char*)sA + row*128 + ks*64 + ((lane>>4)*16));
      }
      #pragma unroll
      for (int n=0;n<4;n++){
        int row = wc*64 + n*16 + (lane & 15);
        bfr[n] = *(const short8*)((const char*)sB + row*128 + ks*64 + ((lane>>4)*16));
      }
      #pragma unroll
      for (int m=0;m<4;m++){
        #pragma unroll
        for (int n=0;n<4;n++)
          acc[m][n] = __builtin_amdgcn_mfma_f32_16x16x32_bf16(af[m], bfr[n], acc[m][n], 0, 0, 0);
      }
    }
    __syncthreads();
  }
  int rowbase = o0 + wr*64;
  #pragma unroll
  for (int m=0;m<4;m++){
    int o = rowbase + m*16 + ((lane>>4)*4);
    #pragma unroll
    for (int n=0;n<4;n++){
      int t = t0 + wc*64 + n*16 + (lane & 15);
      f32x4 v = acc[m][n];
      if (o < C_){
        int h = o >> 6, d = o & 63;
        unsigned short* p = Kb + (((size_t)(b*NH + h)*T_ + t)*DH + d);
        short4v s; s.x=(short)f2bf(v.x); s.y=(short)f2bf(v.y);
        s.z=(short)f2bf(v.z); s.w=(short)f2bf(v.w);
        *(short4v*)p = s;
      } else if (o < 2*C_){
        int oo = o - C_;
        int h = oo >> 6, d = oo & 63;
        unsigned short* p = Vt + (((size_t)(b*NH + h)*DH + d)*T_ + t);
        p[0]    = f2bf(v.x);
        p[T_]   = f2bf(v.y);
        p[2*T_] = f2bf(v.z);
        p[3*T_] = f2bf(v.w);
      } else {
        int oo = o - 2*C_;
        int h = oo >> 6, d = oo & 63;
        unsigned short* p = Qb + (((size_t)(b*NH + h)*T_ + t)*DH + d);
        short4v s; s.x=(short)f2bf(v.x*S2Q); s.y=(short)f2bf(v.y*S2Q);
        s.z=(short)f2bf(v.z*S2Q); s.w=(short)f2bf(v.w*S2Q);
        *(short4v*)p = s;
      }
    }
  }
}

// ---------------- flash attention: 8 waves, QBLK=256, XCD-local bh grouping ----------------
#define KB_ 64

#define GLL(SRC, SHBUF, LOFF) \
  __builtin_amdgcn_global_load_lds((const __attribute__((address_space(1))) void*)(SRC), \
      (__attribute__((address_space(3))) void*)((__attribute__((address_space(3))) char*)(SHBUF) + (LOFF)), 16, 0, 0)

// proven per-stream softmax + P-write
#define SMAX(SACC, MRUN, LPART, ACCO, PBASE) do {                                      \
  float m0_ = fmaxf(fmaxf(SACC[0][0],SACC[0][1]),SACC[0][2]);                          \
  float m1_ = fmaxf(fmaxf(SACC[0][3],SACC[1][0]),SACC[1][1]);                          \
  float m2_ = fmaxf(fmaxf(SACC[1][2],SACC[1][3]),SACC[2][0]);                          \
  float m3_ = fmaxf(fmaxf(SACC[2][1],SACC[2][2]),SACC[2][3]);                          \
  float m4_ = fmaxf(fmaxf(SACC[3][0],SACC[3][1]),SACC[3][2]);                          \
  float pmax = fmaxf(fmaxf(fmaxf(m0_,m1_),m2_), fmaxf(fmaxf(m3_,m4_),SACC[3][3]));     \
  if (!__all(pmax - MRUN <= 8.0f)){                                                    \
    float pm = fmaxf(pmax, __shfl_xor(pmax, 16));                                      \
    pm = fmaxf(pm, __shfl_xor(pm, 32));                                                \
    float mnew = fmaxf(MRUN, pm);                                                      \
    float alpha = __builtin_amdgcn_exp2f(MRUN - mnew);                                 \
    MRUN = mnew;                                                                       \
    LPART *= alpha;                                                                    \
    _Pragma("unroll")                                                                  \
    for (int r=0;r<4;r++){                                                             \
      float ar = __shfl(alpha, lg*4 + r);                                              \
      _Pragma("unroll")                                                                \
      for (int nd=0; nd<4; nd++) ACCO[nd][r] *= ar;                                    \
    }                                                                                  \
  }                                                                                    \
  float ps_ = 0.f;                                                                     \
  _Pragma("unroll")                                                                    \
  for (int n=0;n<4;n++){                                                               \
    float p0 = __builtin_amdgcn_exp2f(SACC[n][0] - MRUN);                              \
    float p1 = __builtin_amdgcn_exp2f(SACC[n][1] - MRUN);                              \
    float p2 = __builtin_amdgcn_exp2f(SACC[n][2] - MRUN);                              \
    float p3 = __builtin_amdgcn_exp2f(SACC[n][3] - MRUN);                              \
    ps_ += p0 + p1 + p2 + p3;                                                          \
    unsigned int w0, w1;                                                               \
    asm volatile("v_cvt_pk_bf16_f32 %0, %1, %2" : "=v"(w0) : "v"(p0), "v"(p1));        \
    asm volatile("v_cvt_pk_bf16_f32 %0, %1, %2" : "=v"(w1) : "v"(p2), "v"(p3));        \
    uint2 w; w.x = w0; w.y = w1;                                                       \
    *(uint2*)(sPw + (PBASE) + l15*128 + pOff[n]) = w;                                  \
  }                                                                                    \
  LPART += ps_;                                                                        \
} while(0)

#define TILE(CBUF, BUSE, BPRE, POFF, DOSTAGE, DOPRE) do {                              \
  if (DOSTAGE) {                                                                       \
    GLL(srcK, &sK[(CBUF)^1][0], L0);                                                   \
    GLL(srcV, &sV[(CBUF)^1][0], L0);                                                   \
    srcK += 8192; srcV += 128;                                                         \
  }                                                                                    \
  if (DOPRE) {                                                                         \
    _Pragma("unroll")                                                                  \
    for (int n=0;n<4;n++) BPRE[n] = *(const f32x4*)(bptr + (POFF) + n*16);             \
  }                                                                                    \
  const char* sKb = (const char*)&sK[CBUF][0] + l15*128;                               \
  const char* sVb = (const char*)&sV[CBUF][0] + l15*128;                               \
  f32x4 sacc0[4], sacc1[4];                                                            \
  __builtin_amdgcn_s_setprio(1);                                                       \
  _Pragma("unroll")                                                                    \
  for (int n=0;n<4;n++){                                                               \
    short8 kf0 = *(const short8*)(sKb + n*2048 + cA);                                  \
    short8 kf1 = *(const short8*)(sKb + n*2048 + (cA ^ 64));                           \
    sacc0[n] = __builtin_amdgcn_mfma_f32_16x16x32_bf16(kf0, qf00, BUSE[n], 0,0,0);     \
    sacc0[n] = __builtin_amdgcn_mfma_f32_16x16x32_bf16(kf1, qf01, sacc0[n], 0,0,0);    \
    sacc1[n] = __builtin_amdgcn_mfma_f32_16x16x32_bf16(kf0, qf10, BUSE[n], 0,0,0);     \
    sacc1[n] = __builtin_amdgcn_mfma_f32_16x16x32_bf16(kf1, qf11, sacc1[n], 0,0,0);    \
  }                                                                                    \
  __builtin_amdgcn_s_setprio(0);                                                       \
  SMAX(sacc0, mrun0, lpart0, acco0, 0);                                                \
  SMAX(sacc1, mrun1, lpart1, acco1, 2048);                                             \
  asm volatile("s_waitcnt lgkmcnt(0)" ::: "memory");                                   \
  __builtin_amdgcn_sched_barrier(0);                                                   \
  __builtin_amdgcn_s_setprio(1);                                                       \
  _Pragma("unroll")                                                                    \
  for (int ks=0; ks<2; ks++){                                                          \
    short8 pf0 = *(const short8*)(sPw + l15*128 + (cA ^ (ks<<6)));                     \
    short8 pf1 = *(const short8*)(sPw + 2048 + l15*128 + (cA ^ (ks<<6)));              \
    _Pragma("unroll")                                                                  \
    for (int nd=0; nd<4; nd++){                                                        \
      short8 vf = *(const short8*)(sVb + nd*2048 + (cA ^ (ks<<6)));                    \
      acco0[nd] = __builtin_amdgcn_mfma_f32_16x16x32_bf16(pf0, vf, acco0[nd], 0,0,0);  \
      acco1[nd] = __builtin_amdgcn_mfma_f32_16x16x32_bf16(pf1, vf, acco1[nd], 0,0,0);  \
    }                                                                                  \
  }                                                                                    \
  __builtin_amdgcn_s_setprio(0);                                                       \
  __syncthreads();                                                                     \
} while(0)

#define EPI(ACCO, LPART, TOFF) do {                                                    \
  float lt = LPART + __shfl_xor(LPART, 16);                                            \
  lt += __shfl_xor(lt, 32);                                                            \
  float rl[4];                                                                         \
  _Pragma("unroll")                                                                    \
  for (int r=0;r<4;r++) rl[r] = 1.0f / __shfl(lt, lg*4 + r);                           \
  _Pragma("unroll")                                                                    \
  for (int nd=0; nd<4; nd++){                                                          \
    int d = nd*16 + l15;                                                               \
    int c = h*64 + d;                                                                  \
    float4 v;                                                                          \
    v.x = ACCO[nd][0] * rl[0];                                                         \
    v.y = ACCO[nd][1] * rl[1];                                                         \
    v.z = ACCO[nd][2] * rl[2];                                                         \
    v.w = ACCO[nd][3] * rl[3];                                                         \
    size_t off = ((size_t)b*C_ + c)*T_ + (size_t)qblk*256 + wave*32 + (TOFF) + lg*4;   \
    *(float4*)(out + off) = v;                                                         \
  }                                                                                    \
} while(0)

__global__ __launch_bounds__(512) void attn_kernel(const unsigned short* __restrict__ Qb,
    const unsigned short* __restrict__ Kb, const unsigned short* __restrict__ Vt,
    const float* __restrict__ fbias, float* __restrict__ out){
  __shared__ unsigned short sK[2][KB_*DH];      // [key][d] swizzled, dbuf (8KB each)
  __shared__ unsigned short sV[2][KB_*DH];      // [d][key] swizzled, dbuf
  __shared__ unsigned short sP[8][2][16*KB_];   // per-wave, per-stream [q(l15)][key] swizzled
  // XCD-local remap: all 8 qblk-blocks of one bh share L%8 -> same XCD L2 holds its K/V panel.
  // Bijective over 512 = 8 qblk x 64 bh.
  const int Lid = blockIdx.x;
  const int xcd = Lid & 7, jj = Lid >> 3;
  const int bh = ((jj & 7) << 3) | xcd;
  const int qblk = jj >> 3;
  const int b = bh >> 4;
  const int tid = threadIdx.x, lane = tid & 63, wave = tid >> 6;
  const int l15 = lane & 15, lg = lane >> 4;
  const int rsw = l15 & 7;
  const int cA = (lg ^ rsw) << 4;
  const unsigned short* Kbase = Kb + (size_t)bh*T_*DH;
  const unsigned short* Vbase = Vt + (size_t)bh*DH*T_;
  const float* bptr = fbias + (size_t)b*T_ + lg*4;
  // Q: two 16-row streams per wave (wave owns 32 q-rows of the 256-row block)
  const int qrow0 = qblk*256 + wave*32 + l15;
  const unsigned short* Qp0 = Qb + ((size_t)bh*T_ + qrow0)*DH + lg*8;
  const unsigned short* Qp1 = Qp0 + 16*DH;
  short8 qf00 = *(const short8*)(Qp0);
  short8 qf01 = *(const short8*)(Qp0 + 32);
  short8 qf10 = *(const short8*)(Qp1);
  short8 qf11 = *(const short8*)(Qp1 + 32);
  f32x4 acco0[4] = {};                 // stream 0: out[q=lg*4+r][d=nd*16+l15]
  f32x4 acco1[4] = {};                 // stream 1
  float mrun0 = -1e30f, lpart0 = 0.f;
  float mrun1 = -1e30f, lpart1 = 0.f;
  // staging: one 1KB slice per wave (8 waves cover the 8KB tile); inverse-swizzled source
  const int L0  = wave*1024;
  const int Ll0 = L0 + lane*16;
  const int row0 = Ll0 >> 7;
  const int cg0 = ((Ll0 >> 4) & 7) ^ (row0 & 7);
  const char* srcK = (const char*)Kbase + row0*128 + cg0*16;
  const char* srcV = (const char*)Vbase + (size_t)row0*(T_*2) + cg0*16;
  char* sPw = (char*)&sP[wave][0][0];
  int pOff[4];
  #pragma unroll
  for (int n=0;n<4;n++) pOff[n] = (((n*2 + (lg>>1)) ^ rsw) << 4) | ((lg & 1) << 3);

  // prologue: stage tile 0, preload bias(0)
  GLL(srcK, &sK[0][0], L0);
  GLL(srcV, &sV[0][0], L0);
  srcK += 8192; srcV += 128;
  f32x4 biasA[4], biasB[4];
  #pragma unroll
  for (int n=0;n<4;n++) biasA[n] = *(const f32x4*)(bptr + n*16);
  __syncthreads();

  for (int kt2 = 0; kt2 < T_/KB_/2 - 1; kt2++){
    TILE(0, biasA, biasB,  64, true, true);
    TILE(1, biasB, biasA, 128, true, true);
    bptr += 128;
  }
  TILE(0, biasA, biasB, 64, true, true);    // kt=30, stages tile 31
  TILE(1, biasB, biasA,  0, false, false);  // kt=31

  int h = bh & 15;
  EPI(acco0, lpart0, 0);
  EPI(acco1, lpart1, 16);
}

extern "C" void kernel_launch(void* const* d_in, const int* in_sizes, int n_in,
                              void* d_out, int out_size, void* d_ws, size_t ws_size,
                              hipStream_t stream) {
  const float* x    = (const float*)d_in[0];
  const int*   mask = (const int*)d_in[1];
  const float* Wmem = (const float*)d_in[2];
  const float* Wq   = (const float*)d_in[3];
  float* out = (float*)d_out;

  unsigned short* ws = (unsigned short*)d_ws;
  unsigned short* xT = ws;                                   // B*T*C
  unsigned short* Wc = xT + (size_t)B_*T_*C_;                // TC*C
  unsigned short* Qb = Wc + (size_t)TC*C_;                   // B*NH*T*DH
  unsigned short* Kb = Qb + (size_t)B_*NH*T_*DH;
  unsigned short* Vt = Kb + (size_t)B_*NH*T_*DH;
  float* fbias = (float*)(Vt + (size_t)B_*NH*T_*DH);         // B*T floats

  cast_w_kernel<<<dim3(TC*C_/1024), dim3(256), 0, stream>>>(Wmem, Wq, Wc);
  mask_bias_kernel<<<dim3(B_*T_/256), dim3(256), 0, stream>>>(mask, fbias);
  transpose_x_kernel<<<dim3(T_/32, C_/32, B_), dim3(32,8), 0, stream>>>(x, xT);
  proj_gemm_kernel<<<dim3((TC/PBM)*(T_/PBN), B_), dim3(256), 0, stream>>>(Wc, xT, Kb, Vt, Qb);
  attn_kernel<<<dim3((T_/256)*(B_*NH)), dim3(512), 0, stream>>>(Qb, Kb, Vt, fbias, out);
}

// Round 12
// 206.607 us; speedup vs baseline: 1.0863x; 1.0010x over previous
//
#include <hip/hip_runtime.h>

#define B_ 4
#define C_ 1024
#define T_ 2048
#define NH 16
#define DH 64
#define TC 3072   // 3*C: rows [0,2048)=W_mem (K then V), [2048,3072)=W_q

typedef __attribute__((ext_vector_type(8))) short short8;
typedef __attribute__((ext_vector_type(4))) short short4v;
typedef __attribute__((ext_vector_type(4))) float f32x4;
typedef __attribute__((ext_vector_type(16))) float f32x16;
typedef __attribute__((ext_vector_type(2))) unsigned int u32x2;
typedef __attribute__((ext_vector_type(4))) unsigned int u32x4;

#define S2Q 0.1803368801111204f   // 0.125 * log2(e), folded into Q at projection

static __device__ __forceinline__ unsigned short f2bf(float f){
  unsigned int u = __builtin_bit_cast(unsigned int, f);
  u += 0x7fffu + ((u >> 16) & 1u);
  return (unsigned short)(u >> 16);
}

// ---------------- cast W_mem||W_q -> bf16 Wc[3072][1024] ----------------
__global__ __launch_bounds__(256) void cast_w_kernel(const float* __restrict__ Wmem,
                                                     const float* __restrict__ Wq,
                                                     unsigned short* __restrict__ Wc){
  size_t base = ((size_t)blockIdx.x*256 + threadIdx.x)*4;
  float4 v;
  if (base < (size_t)2048*1024) v = *(const float4*)(Wmem + base);
  else                          v = *(const float4*)(Wq + (base - (size_t)2048*1024));
  short4v o;
  o.x = (short)f2bf(v.x); o.y = (short)f2bf(v.y);
  o.z = (short)f2bf(v.z); o.w = (short)f2bf(v.w);
  *(short4v*)(Wc + base) = o;
}

// ---------------- mask -> additive float bias (exact ref semantics) ----------------
__global__ __launch_bounds__(256) void mask_bias_kernel(const int* __restrict__ mask,
                                                        float* __restrict__ fbias){
  int i = blockIdx.x*256 + threadIdx.x;
  fbias[i] = mask[i] ? 0.f : -1e30f;
}

// ---------------- transpose-cast x[B][C][T] f32 -> xT[B][T][C] bf16 ----------------
__global__ __launch_bounds__(256) void transpose_x_kernel(const float* __restrict__ x,
                                                          unsigned short* __restrict__ xT){
  __shared__ float tile[32][33];
  int b = blockIdx.z;
  int c0 = blockIdx.y*32, t0 = blockIdx.x*32;
  int tx = threadIdx.x, ty = threadIdx.y;
  const float* xp = x + ((size_t)b*C_ + c0)*T_ + t0;
  #pragma unroll
  for (int i=0;i<4;i++) tile[ty+8*i][tx] = xp[(size_t)(ty+8*i)*T_ + tx];
  __syncthreads();
  unsigned short* op = xT + ((size_t)b*T_ + t0)*C_ + c0;
  int cp = tx & 15, tw = tx >> 4;
  #pragma unroll
  for (int i=0;i<2;i++){
    int trow = ty + 8*tw + 16*i;
    unsigned int pk = (unsigned int)f2bf(tile[2*cp][trow])
                    | ((unsigned int)f2bf(tile[2*cp+1][trow]) << 16);
    *(unsigned int*)(op + (size_t)trow*C_ + 2*cp) = pk;
  }
}

// ---------------- projection GEMM (m97 structure; Q pre-scaled by S2Q) ----------------
#define PBM 128
#define PBN 128
#define PBK 64

__global__ __launch_bounds__(256) void proj_gemm_kernel(const unsigned short* __restrict__ Wc,
    const unsigned short* __restrict__ xT,
    unsigned short* __restrict__ Kb, unsigned short* __restrict__ Vt,
    unsigned short* __restrict__ Qb){
  __shared__ unsigned short sA[PBM*PBK];
  __shared__ unsigned short sB[PBN*PBK];
  int b = blockIdx.y;
  int nbn = T_/PBN;
  int o0 = (int)(blockIdx.x / nbn)*PBM;
  int t0 = (int)(blockIdx.x % nbn)*PBN;
  int tid = threadIdx.x;
  int lane = tid & 63, wave = tid >> 6;
  int wr = wave >> 1, wc = wave & 1;
  f32x4 acc[4][4] = {};
  const unsigned short* Abase = Wc + (size_t)o0*C_;
  const unsigned short* Bbase = xT + ((size_t)b*T_ + t0)*C_;
  auto ldsA = (__attribute__((address_space(3))) char*)sA;
  auto ldsB = (__attribute__((address_space(3))) char*)sB;
  for (int k0=0; k0<C_; k0+=PBK){
    #pragma unroll
    for (int i=0;i<4;i++){
      int L  = wave*4096 + i*1024;
      int Ll = L + lane*16;
      int row = Ll >> 7;
      int jb  = Ll & 127;
      const char* srcA = (const char*)(Abase + (size_t)row*C_ + k0) + jb;
      const char* srcB = (const char*)(Bbase + (size_t)row*C_ + k0) + jb;
      __builtin_amdgcn_global_load_lds((const __attribute__((address_space(1))) void*)srcA,
                                       (__attribute__((address_space(3))) void*)(ldsA + L), 16, 0, 0);
      __builtin_amdgcn_global_load_lds((const __attribute__((address_space(1))) void*)srcB,
                                       (__attribute__((address_space(3))) void*)(ldsB + L), 16, 0, 0);
    }
    __syncthreads();
    #pragma unroll
    for (int ks=0; ks<2; ks++){
      short8 af[4], bfr[4];
      #pragma unroll
      for (int m=0;m<4;m++){
        int row = wr*64 + m*16 + (lane & 15);
        af[m] = *(const short8*)((const char*)sA + row*128 + ks*64 + ((lane>>4)*16));
      }
      #pragma unroll
      for (int n=0;n<4;n++){
        int row = wc*64 + n*16 + (lane & 15);
        bfr[n] = *(const short8*)((const char*)sB + row*128 + ks*64 + ((lane>>4)*16));
      }
      #pragma unroll
      for (int m=0;m<4;m++){
        #pragma unroll
        for (int n=0;n<4;n++)
          acc[m][n] = __builtin_amdgcn_mfma_f32_16x16x32_bf16(af[m], bfr[n], acc[m][n], 0, 0, 0);
      }
    }
    __syncthreads();
  }
  int rowbase = o0 + wr*64;
  #pragma unroll
  for (int m=0;m<4;m++){
    int o = rowbase + m*16 + ((lane>>4)*4);
    #pragma unroll
    for (int n=0;n<4;n++){
      int t = t0 + wc*64 + n*16 + (lane & 15);
      f32x4 v = acc[m][n];
      if (o < C_){
        int h = o >> 6, d = o & 63;
        unsigned short* p = Kb + (((size_t)(b*NH + h)*T_ + t)*DH + d);
        short4v s; s.x=(short)f2bf(v.x); s.y=(short)f2bf(v.y);
        s.z=(short)f2bf(v.z); s.w=(short)f2bf(v.w);
        *(short4v*)p = s;
      } else if (o < 2*C_){
        int oo = o - C_;
        int h = oo >> 6, d = oo & 63;
        unsigned short* p = Vt + (((size_t)(b*NH + h)*DH + d)*T_ + t);
        p[0]    = f2bf(v.x);
        p[T_]   = f2bf(v.y);
        p[2*T_] = f2bf(v.z);
        p[3*T_] = f2bf(v.w);
      } else {
        int oo = o - 2*C_;
        int h = oo >> 6, d = oo & 63;
        unsigned short* p = Qb + (((size_t)(b*NH + h)*T_ + t)*DH + d);
        short4v s; s.x=(short)f2bf(v.x*S2Q); s.y=(short)f2bf(v.y*S2Q);
        s.z=(short)f2bf(v.z*S2Q); s.w=(short)f2bf(v.w*S2Q);
        *(short4v*)p = s;
      }
    }
  }
}

// ---------------- flash attention: 32x32 MFMA, in-register P via permlane32_swap ----------------
// 4 waves x 32 q-rows (QBLK=128). S^T = mfma32(K,Q): lane owns q=lane&31, rows=keys
// (row=(r&3)+8*(r>>2)+4h). PV A-operand also row=q=lane&31 -> P stays lane-local;
// only the h-half exchange is needed: (X,Y)=permlane32_swap(W[2e][w],W[2e+1][w]),
// A-frag = [X0,X1,Y0,Y1] with m=2(kstep&1)+h. No P LDS, no mid-tile lgkm drain.
#define KB_ 64

#define GLL(SRC, SHBUF, LOFF) \
  __builtin_amdgcn_global_load_lds((const __attribute__((address_space(1))) void*)(SRC), \
      (__attribute__((address_space(3))) void*)((__attribute__((address_space(3))) char*)(SHBUF) + (LOFF)), 16, 0, 0)

#define TILE(CBUF, POFF, DOSTAGE) do {                                                 \
  if (DOSTAGE) {                                                                       \
    GLL(srcK0, &sK[(CBUF)^1][0], L0);                                                  \
    GLL(srcK1, &sK[(CBUF)^1][0], L0 + 1024);                                           \
    GLL(srcV0, &sV[(CBUF)^1][0], L0);                                                  \
    GLL(srcV1, &sV[(CBUF)^1][0], L0 + 1024);                                           \
    srcK0 += 8192; srcK1 += 8192; srcV0 += 128; srcV1 += 128;                          \
  }                                                                                    \
  f32x4 bbA[4], bbB[4];                                                                \
  _Pragma("unroll")                                                                    \
  for (int m=0;m<4;m++){                                                               \
    bbA[m] = *(const f32x4*)(bptr + (POFF) + m*8);                                     \
    bbB[m] = *(const f32x4*)(bptr + (POFF) + 32 + m*8);                                \
  }                                                                                    \
  const char* sKb = (const char*)&sK[CBUF][0] + l31*128;                               \
  const char* sVb = (const char*)&sV[CBUF][0] + l31*128;                               \
  f32x16 s0 = {}, s1 = {};                                                             \
  __builtin_amdgcn_s_setprio(1);                                                       \
  _Pragma("unroll")                                                                    \
  for (int kc=0;kc<4;kc++){                                                            \
    int co = (((kc<<1)|h) ^ rsw) << 4;                                                 \
    short8 kf0 = *(const short8*)(sKb + co);                                           \
    short8 kf1 = *(const short8*)(sKb + 4096 + co);                                    \
    s0 = __builtin_amdgcn_mfma_f32_32x32x16_bf16(kf0, qf[kc], s0, 0,0,0);              \
    s1 = __builtin_amdgcn_mfma_f32_32x32x16_bf16(kf1, qf[kc], s1, 0,0,0);              \
  }                                                                                    \
  __builtin_amdgcn_s_setprio(0);                                                       \
  float p[32];                                                                         \
  _Pragma("unroll")                                                                    \
  for (int m=0;m<4;m++){                                                               \
    _Pragma("unroll")                                                                  \
    for (int s=0;s<4;s++){                                                             \
      p[m*4+s]    = s0[m*4+s] + bbA[m][s];                                             \
      p[16+m*4+s] = s1[m*4+s] + bbB[m][s];                                             \
    }                                                                                  \
  }                                                                                    \
  float pmax = p[0];                                                                   \
  _Pragma("unroll")                                                                    \
  for (int j=1;j<32;j++) pmax = fmaxf(pmax, p[j]);                                     \
  if (!__all(pmax - mrun <= 8.0f)){                                                    \
    float pm = fmaxf(pmax, __shfl_xor(pmax, 32));                                      \
    float mnew = fmaxf(mrun, pm);                                                      \
    float alpha = __builtin_amdgcn_exp2f(mrun - mnew);                                 \
    mrun = mnew; lpart *= alpha;                                                       \
    _Pragma("unroll")                                                                  \
    for (int r=0;r<16;r++){                                                            \
      float ar = __shfl(alpha, (r&3) + 8*(r>>2) + 4*h);                                \
      acco0[r] *= ar; acco1[r] *= ar;                                                  \
    }                                                                                  \
  }                                                                                    \
  float ps_ = 0.f;                                                                     \
  _Pragma("unroll")                                                                    \
  for (int j=0;j<32;j++){ p[j] = __builtin_amdgcn_exp2f(p[j] - mrun); ps_ += p[j]; }   \
  lpart += ps_;                                                                        \
  unsigned int Wp[2][4][2];                                                            \
  _Pragma("unroll")                                                                    \
  for (int m=0;m<4;m++){                                                               \
    asm volatile("v_cvt_pk_bf16_f32 %0, %1, %2" : "=v"(Wp[0][m][0]) : "v"(p[4*m]),    "v"(p[4*m+1]));  \
    asm volatile("v_cvt_pk_bf16_f32 %0, %1, %2" : "=v"(Wp[0][m][1]) : "v"(p[4*m+2]),  "v"(p[4*m+3]));  \
    asm volatile("v_cvt_pk_bf16_f32 %0, %1, %2" : "=v"(Wp[1][m][0]) : "v"(p[16+4*m]), "v"(p[16+4*m+1]));\
    asm volatile("v_cvt_pk_bf16_f32 %0, %1, %2" : "=v"(Wp[1][m][1]) : "v"(p[16+4*m+2]),"v"(p[16+4*m+3]));\
  }                                                                                    \
  __builtin_amdgcn_s_setprio(1);                                                       \
  _Pragma("unroll")                                                                    \
  for (int kb=0;kb<2;kb++){                                                            \
    _Pragma("unroll")                                                                  \
    for (int e=0;e<2;e++){                                                             \
      u32x2 x0 = __builtin_amdgcn_permlane32_swap(Wp[kb][2*e][0], Wp[kb][2*e+1][0], 0, 0); \
      u32x2 x1 = __builtin_amdgcn_permlane32_swap(Wp[kb][2*e][1], Wp[kb][2*e+1][1], 0, 0); \
      u32x4 pw; pw.x = x0.x; pw.y = x1.x; pw.z = x0.y; pw.w = x1.y;                    \
      short8 pf = __builtin_bit_cast(short8, pw);                                      \
      int vo = (((((kb<<1)|e)<<1)|h) ^ rsw) << 4;                                      \
      short8 vf0 = *(const short8*)(sVb + vo);                                         \
      short8 vf1 = *(const short8*)(sVb + 4096 + vo);                                  \
      acco0 = __builtin_amdgcn_mfma_f32_32x32x16_bf16(pf, vf0, acco0, 0,0,0);          \
      acco1 = __builtin_amdgcn_mfma_f32_32x32x16_bf16(pf, vf1, acco1, 0,0,0);          \
    }                                                                                  \
  }                                                                                    \
  __builtin_amdgcn_s_setprio(0);                                                       \
  __syncthreads();                                                                     \
} while(0)

__global__ __launch_bounds__(256) void attn_kernel(const unsigned short* __restrict__ Qb,
    const unsigned short* __restrict__ Kb, const unsigned short* __restrict__ Vt,
    const float* __restrict__ fbias, float* __restrict__ out){
  __shared__ unsigned short sK[2][KB_*DH];   // [key][d] swizzled, dbuf (8KB each)
  __shared__ unsigned short sV[2][KB_*DH];   // [d][key] swizzled, dbuf
  // XCD-local remap (r10-proven, 1024 blocks): all 16 qblk of one bh share L%8.
  const int Lid = blockIdx.x;
  const int xcd = Lid & 7, jj = Lid >> 3;
  const int bh = ((jj & 7) << 3) | xcd;
  const int qblk = jj >> 3;
  const int b = bh >> 4;
  const int tid = threadIdx.x, lane = tid & 63, wave = tid >> 6;
  const int l31 = lane & 31, h = lane >> 5;
  const int rsw = l31 & 7;
  const unsigned short* Kbase = Kb + (size_t)bh*T_*DH;
  const unsigned short* Vbase = Vt + (size_t)bh*DH*T_;
  const float* bptr = fbias + (size_t)b*T_ + 4*h;
  // Q B-fragments: col=q=l31, k-elems d = kc*16 + h*8 + j
  const int qrow = qblk*128 + wave*32 + l31;
  const unsigned short* Qp = Qb + ((size_t)bh*T_ + qrow)*DH + h*8;
  short8 qf[4];
  #pragma unroll
  for (int kc=0;kc<4;kc++) qf[kc] = *(const short8*)(Qp + kc*16);
  f32x16 acco0 = {}, acco1 = {};     // O[q-rows][d = db*32 + l31], db=0/1
  float mrun = -1e30f, lpart = 0.f;  // per lane: q = l31 (dup across h)
  // staging (r8-proven four-pointer form, 4 waves x 2KB slices)
  const int L0  = wave*2048;
  const int Ll0 = L0 + lane*16, Ll1 = Ll0 + 1024;
  const int row0 = Ll0 >> 7, row1 = Ll1 >> 7;
  const int cg0 = ((Ll0 >> 4) & 7) ^ (row0 & 7);
  const int cg1 = ((Ll1 >> 4) & 7) ^ (row1 & 7);
  const char* srcK0 = (const char*)Kbase + row0*128 + cg0*16;
  const char* srcK1 = (const char*)Kbase + row1*128 + cg1*16;
  const char* srcV0 = (const char*)Vbase + (size_t)row0*(T_*2) + cg0*16;
  const char* srcV1 = (const char*)Vbase + (size_t)row1*(T_*2) + cg1*16;

  // prologue: stage tile 0
  GLL(srcK0, &sK[0][0], L0);
  GLL(srcK1, &sK[0][0], L0 + 1024);
  GLL(srcV0, &sV[0][0], L0);
  GLL(srcV1, &sV[0][0], L0 + 1024);
  srcK0 += 8192; srcK1 += 8192; srcV0 += 128; srcV1 += 128;
  __syncthreads();

  for (int kt2 = 0; kt2 < T_/KB_/2 - 1; kt2++){
    TILE(0,  0, true);
    TILE(1, 64, true);
    bptr += 128;
  }
  TILE(0,  0, true);    // kt=30, stages tile 31
  TILE(1, 64, false);   // kt=31

  // epilogue
  lpart += __shfl_xor(lpart, 32);
  float inv = 1.0f / lpart;          // valid for q = l31 on every lane
  const int head = bh & 15;
  const int qbase = qblk*128 + wave*32;
  #pragma unroll
  for (int m=0;m<4;m++){
    float rv[4];
    #pragma unroll
    for (int s=0;s<4;s++) rv[s] = __shfl(inv, 8*m + 4*h + s);
    int t = qbase + 8*m + 4*h;
    float4 v0, v1;
    v0.x = acco0[4*m+0]*rv[0]; v0.y = acco0[4*m+1]*rv[1];
    v0.z = acco0[4*m+2]*rv[2]; v0.w = acco0[4*m+3]*rv[3];
    v1.x = acco1[4*m+0]*rv[0]; v1.y = acco1[4*m+1]*rv[1];
    v1.z = acco1[4*m+2]*rv[2]; v1.w = acco1[4*m+3]*rv[3];
    size_t off0 = ((size_t)b*C_ + head*64 + l31)*T_ + t;
    size_t off1 = ((size_t)b*C_ + head*64 + 32 + l31)*T_ + t;
    *(float4*)(out + off0) = v0;
    *(float4*)(out + off1) = v1;
  }
}

extern "C" void kernel_launch(void* const* d_in, const int* in_sizes, int n_in,
                              void* d_out, int out_size, void* d_ws, size_t ws_size,
                              hipStream_t stream) {
  const float* x    = (const float*)d_in[0];
  const int*   mask = (const int*)d_in[1];
  const float* Wmem = (const float*)d_in[2];
  const float* Wq   = (const float*)d_in[3];
  float* out = (float*)d_out;

  unsigned short* ws = (unsigned short*)d_ws;
  unsigned short* xT = ws;                                   // B*T*C
  unsigned short* Wc = xT + (size_t)B_*T_*C_;                // TC*C
  unsigned short* Qb = Wc + (size_t)TC*C_;                   // B*NH*T*DH
  unsigned short* Kb = Qb + (size_t)B_*NH*T_*DH;
  unsigned short* Vt = Kb + (size_t)B_*NH*T_*DH;
  float* fbias = (float*)(Vt + (size_t)B_*NH*T_*DH);         // B*T floats

  cast_w_kernel<<<dim3(TC*C_/1024), dim3(256), 0, stream>>>(Wmem, Wq, Wc);
  mask_bias_kernel<<<dim3(B_*T_/256), dim3(256), 0, stream>>>(mask, fbias);
  transpose_x_kernel<<<dim3(T_/32, C_/32, B_), dim3(32,8), 0, stream>>>(x, xT);
  proj_gemm_kernel<<<dim3((TC/PBM)*(T_/PBN), B_), dim3(256), 0, stream>>>(Wc, xT, Kb, Vt, Qb);
  attn_kernel<<<dim3((T_/128)*(B_*NH)), dim3(256), 0, stream>>>(Qb, Kb, Vt, fbias, out);
}